// Round 3
// baseline (1042.089 us; speedup 1.0000x reference)
//
#include <hip/hip_runtime.h>

// Reference constants
constexpr int   TH    = 8;     // TREE_HEIGHT
constexpr int   NNEG  = 8;     // N_NEG
constexpr int   HID4  = 256;   // HIDDEN in float4 units (1024/4)
constexpr int   FOLD4 = 128;   // folded row (512 floats) in float4 units
constexpr float SCR_F = 6.2831853071795864769f; // 2*pi

// ---------------------------------------------------------------------------
// Pass 1a: zero the node flags (ws is poisoned every iteration).
// ---------------------------------------------------------------------------
__global__ __launch_bounds__(256)
void flag_zero(int* __restrict__ flags, int n)
{
    for (int i = blockIdx.x * 256 + threadIdx.x; i < n; i += gridDim.x * 256)
        flags[i] = 0;
}

// ---------------------------------------------------------------------------
// Pass 1b: mark every node row actually referenced (p2 rows + all neg rows).
// ~48% of the 200K rows never appear; the fold pass skips them.
// ---------------------------------------------------------------------------
__global__ __launch_bounds__(256)
void flag_set(const int* __restrict__ pos_path,
              const int* __restrict__ neg_path,
              int* __restrict__ flags, int batch)
{
    const int tid = blockIdx.x * 256 + threadIdx.x;
    const int np2 = batch * TH;                 // p2 references
    const int tot = np2 + batch * NNEG * TH;    // + neg references
    if (tid >= tot) return;
    int r;
    if (tid < np2) {
        const int b = tid / TH, h = tid % TH;
        r = pos_path[b * 2 * TH + TH + h];      // p2[b][h]
    } else {
        r = neg_path[tid - np2];
    }
    flags[r] = 1;                               // benign write races
}

// ---------------------------------------------------------------------------
// Pass 2: fold the embedding table for referenced rows only:
//   folded[r][c] = emb[r][c] + emb[r][512+c]   (the x0.5 is applied later,
//   exactly as the previous kernels did: accumulate (lo+hi), scale once).
// Ascending-row streaming read (~427 MB) + write (~214 MB) at HBM rate.
// 2048 blocks x 4 waves; wave w handles rows w, w+8192, ...
// ---------------------------------------------------------------------------
__global__ __launch_bounds__(256)
void fold_kernel(const float* __restrict__ emb,
                 const int*   __restrict__ flags,
                 float*       __restrict__ folded,
                 int n_nodes)
{
    const int lane = threadIdx.x & 63;
    const int wave = blockIdx.x * 4 + (threadIdx.x >> 6);
    const int nwaves = gridDim.x * 4;

    const float4* __restrict__ embv = (const float4*)emb;
    float4* __restrict__ fv = (float4*)folded;

    for (int r = wave; r < n_nodes; r += nwaves) {
        if (!flags[r]) continue;
        const float4* row = embv + (long)r * HID4;
        const float4 a0 = row[lane];        // lo half, f4 cols [0,64)
        const float4 a1 = row[64 + lane];   // lo half, f4 cols [64,128)
        const float4 a2 = row[128 + lane];  // hi half
        const float4 a3 = row[192 + lane];  // hi half
        float4 o0, o1;
        o0.x = a0.x + a2.x; o0.y = a0.y + a2.y;
        o0.z = a0.z + a2.z; o0.w = a0.w + a2.w;
        o1.x = a1.x + a3.x; o1.y = a1.y + a3.y;
        o1.z = a1.z + a3.z; o1.w = a1.w + a3.w;
        fv[(long)r * FOLD4 + lane]      = o0;
        fv[(long)r * FOLD4 + 64 + lane] = o1;
    }
}

// ---------------------------------------------------------------------------
// Pass 3: per-batch prep, one wave per batch element.
//   sp2[b][512] = sum of folded p2 rows (16 x 1KB loads from folded table)
//   C[b][n]     = (diff_pos - 1 - (raw_n==0)) * 2pi
// ---------------------------------------------------------------------------
__global__ __launch_bounds__(64, 2)
void prep_kernel(const float* __restrict__ folded,
                 const int*   __restrict__ pos_path,
                 const int*   __restrict__ neg_path,
                 float*       __restrict__ sp2_out,   // [BATCH][512]
                 float*       __restrict__ C_out)     // [BATCH][NNEG]
{
    const int b = blockIdx.x;
    const int l = threadIdx.x;          // 0..63

    if (l < NNEG) {
        int p1v[TH], p2v[TH];
#pragma unroll
        for (int i = 0; i < TH; i++) {
            p1v[i] = pos_path[b * 2 * TH + i];
            p2v[i] = pos_path[b * 2 * TH + TH + i];
        }
        int inter_pos = 0;
#pragma unroll
        for (int i = 0; i < TH; i++) {
            bool f = false;
#pragma unroll
            for (int j = 0; j < TH; j++) f = f || (p1v[i] == p2v[j]);
            inter_pos += f ? 1 : 0;
        }
        const float diff_pos = fmaxf((float)(TH - inter_pos), 1.0f);

        const int n = l;
        int negj[TH];
#pragma unroll
        for (int j = 0; j < TH; j++)
            negj[j] = neg_path[(b * NNEG + n) * TH + j];

        int inter_n = 0;
#pragma unroll
        for (int i = 0; i < TH; i++) {
            bool f = false;
#pragma unroll
            for (int j = 0; j < TH; j++) f = f || (p1v[i] == negj[j]);
            inter_n += f ? 1 : 0;
        }
        const int raw = TH - inter_n;   // diff_neg_raw (integer, >= 0)
        C_out[b * NNEG + n] = (diff_pos - 1.0f - (raw == 0 ? 1.0f : 0.0f)) * SCR_F;
    }

    const float4* __restrict__ fv = (const float4*)folded;
    float4 s0 = {0.f, 0.f, 0.f, 0.f};
    float4 s1 = {0.f, 0.f, 0.f, 0.f};
#pragma unroll
    for (int h = 0; h < TH; h++) {
        const int r = pos_path[b * 2 * TH + TH + h];   // p2[h], wave-uniform
        const float4* row = fv + (long)r * FOLD4;
        const float4 f0 = row[l];
        const float4 f1 = row[64 + l];
        s0.x += f0.x; s0.y += f0.y; s0.z += f0.z; s0.w += f0.w;
        s1.x += f1.x; s1.y += f1.y; s1.z += f1.z; s1.w += f1.w;
    }
    float4* sp2v = (float4*)sp2_out;
    sp2v[(long)b * FOLD4 + l]      = s0;
    sp2v[(long)b * FOLD4 + 64 + l] = s1;
}

// ---------------------------------------------------------------------------
// Pass 4: one wave per (batch, neg) pair -> 16384 blocks x 64 threads.
// 8 folded rows x 2KB = 16 x 1KB loads; footprint ~214MB (fits L3).
// ---------------------------------------------------------------------------
__global__ __launch_bounds__(64, 2)
void neg_kernel(const float* __restrict__ folded,
                const int*   __restrict__ neg_path,
                const float* __restrict__ sp2_in,    // [BATCH][512]
                const float* __restrict__ C_in,      // [BATCH][NNEG]
                float*       __restrict__ partial,   // [BATCH*NNEG]
                int batch)
{
    const int bn = blockIdx.x;
    const int b  = bn % batch;          // batch index
    const int n  = bn / batch;          // neg index
    const int l  = threadIdx.x;         // 0..63
    const int idx = b * NNEG + n;

    const int4* __restrict__ npv = (const int4*)(neg_path + (long)idx * TH);
    const int4 nlo = npv[0];
    const int4 nhi = npv[1];
    const int ridx[TH] = {nlo.x, nlo.y, nlo.z, nlo.w, nhi.x, nhi.y, nhi.z, nhi.w};
    const float c = C_in[idx];

    const float4* __restrict__ fv = (const float4*)folded;
    float4 s0 = {0.f, 0.f, 0.f, 0.f};
    float4 s1 = {0.f, 0.f, 0.f, 0.f};
#pragma unroll
    for (int h = 0; h < TH; h++) {
        const float4* row = fv + (long)ridx[h] * FOLD4;
        const float4 f0 = row[l];
        const float4 f1 = row[64 + l];
        s0.x += f0.x; s0.y += f0.y; s0.z += f0.z; s0.w += f0.w;
        s1.x += f1.x; s1.y += f1.y; s1.z += f1.z; s1.w += f1.w;
    }

    const float4* sp2v = (const float4*)sp2_in;
    const float4 p0 = sp2v[(long)b * FOLD4 + l];
    const float4 p1 = sp2v[(long)b * FOLD4 + 64 + l];

    float v, a = 0.f;
    v = c + 0.5f * (s0.x - p0.x); v = fmaxf(v, 0.f); a += v * v;
    v = c + 0.5f * (s0.y - p0.y); v = fmaxf(v, 0.f); a += v * v;
    v = c + 0.5f * (s0.z - p0.z); v = fmaxf(v, 0.f); a += v * v;
    v = c + 0.5f * (s0.w - p0.w); v = fmaxf(v, 0.f); a += v * v;
    v = c + 0.5f * (s1.x - p1.x); v = fmaxf(v, 0.f); a += v * v;
    v = c + 0.5f * (s1.y - p1.y); v = fmaxf(v, 0.f); a += v * v;
    v = c + 0.5f * (s1.z - p1.z); v = fmaxf(v, 0.f); a += v * v;
    v = c + 0.5f * (s1.w - p1.w); v = fmaxf(v, 0.f); a += v * v;

#pragma unroll
    for (int off = 32; off > 0; off >>= 1) {
        a += __shfl_down(a, off, 64);
    }
    if (l == 0) partial[idx] = sqrtf(a);
}

// ---------------------------------------------------------------------------
// Pass 5: single-block final reduction of the 16384 partials -> out[0].
// ---------------------------------------------------------------------------
__global__ __launch_bounds__(1024)
void reduce_kernel(const float* __restrict__ partial, int nval,
                   float* __restrict__ out)
{
    const int t = threadIdx.x;
    float s = 0.f;
    for (int i = t; i < nval; i += 1024) s += partial[i];

#pragma unroll
    for (int off = 32; off > 0; off >>= 1) {
        s += __shfl_down(s, off, 64);
    }
    __shared__ float s_red[16];
    const int lane = t & 63;
    const int wid  = t >> 6;
    if (lane == 0) s_red[wid] = s;
    __syncthreads();
    if (t == 0) {
        float tot = 0.f;
#pragma unroll
        for (int w = 0; w < 16; w++) tot += s_red[w];
        out[0] = tot;
    }
}

extern "C" void kernel_launch(void* const* d_in, const int* in_sizes, int n_in,
                              void* d_out, int out_size, void* d_ws, size_t ws_size,
                              hipStream_t stream) {
    const float* emb      = (const float*)d_in[0];
    const int*   pos_path = (const int*)d_in[1];
    const int*   neg_path = (const int*)d_in[2];
    float*       out      = (float*)d_out;

    const int BATCH   = in_sizes[1] / (2 * TH);   // 2048
    const int N_NODES = in_sizes[0] / 1024;       // 200000 (HIDDEN=1024)

    // Workspace layout (~415 MB; ws >= 3 GB)
    float* folded  = (float*)d_ws;                          // N_NODES*512 f32
    int*   flags   = (int*)(folded + (size_t)N_NODES * 512);// N_NODES int
    float* sp2     = (float*)(flags + N_NODES);             // BATCH*512 f32
    float* Cb      = sp2 + (size_t)BATCH * 512;             // BATCH*NNEG f32
    float* partial = Cb  + (size_t)BATCH * NNEG;            // BATCH*NNEG f32

    const int refs = BATCH * (TH + NNEG * TH);              // 147456

    flag_zero<<<512, 256, 0, stream>>>(flags, N_NODES);
    flag_set<<<(refs + 255) / 256, 256, 0, stream>>>(pos_path, neg_path,
                                                     flags, BATCH);
    fold_kernel<<<2048, 256, 0, stream>>>(emb, flags, folded, N_NODES);
    prep_kernel<<<BATCH, 64, 0, stream>>>(folded, pos_path, neg_path, sp2, Cb);
    neg_kernel<<<BATCH * NNEG, 64, 0, stream>>>(folded, neg_path, sp2, Cb,
                                                partial, BATCH);
    reduce_kernel<<<1, 1024, 0, stream>>>(partial, BATCH * NNEG, out);
}